// Round 8
// baseline (139.448 us; speedup 1.0000x reference)
//
#include <hip/hip_runtime.h>
#include <hip/hip_bf16.h>

#define B_ 128
#define S_ 513
#define H_ 256
#define SH_ (S_ * H_)

typedef __attribute__((ext_vector_type(8))) short short8;
typedef __attribute__((ext_vector_type(4))) float f32x4;

// Pack 8 fp32 -> 8 bf16 (RNE) via the HW packed converter.
static __device__ inline short8 pack8(float4 a, float4 b) {
    union { short8 s; __hip_bfloat162 h[4]; } u;
    u.h[0] = __float22bfloat162_rn(make_float2(a.x, a.y));
    u.h[1] = __float22bfloat162_rn(make_float2(a.z, a.w));
    u.h[2] = __float22bfloat162_rn(make_float2(b.x, b.y));
    u.h[3] = __float22bfloat162_rn(make_float2(b.z, b.w));
    return u.s;
}
static __device__ inline short8 pack8v(f32x4 a, f32x4 b) {
    union { short8 s; __hip_bfloat162 h[4]; } u;
    u.h[0] = __float22bfloat162_rn(make_float2(a[0], a[1]));
    u.h[1] = __float22bfloat162_rn(make_float2(a[2], a[3]));
    u.h[2] = __float22bfloat162_rn(make_float2(b[0], b[1]));
    u.h[3] = __float22bfloat162_rn(make_float2(b[2], b[3]));
    return u.s;
}

// Prep: W fp32 -> bf16 in fragment-major layout (m, kc, d, 8) so W fragment
// loads are coalesced (16 lanes -> 256 B run). Also bias sum (256 floats).
__global__ void prep_kernel(const float* __restrict__ W,
                            const float* __restrict__ bias,
                            unsigned short* __restrict__ Wbf,
                            float* __restrict__ bsum) {
    int t = blockIdx.x * 256 + threadIdx.x;
    if (t < 5 * 32 * 256) {                 // one thread per (m, d, kc)
        int m  = t >> 13;                   // t / 8192
        int r  = t & 8191;
        int d  = r >> 5;
        int kc = r & 31;                    // 8-elem k-chunk
        const float* src = W + (((size_t)m * 256 + d) * 256 + kc * 8);
        float4 v0 = *(const float4*)src;
        float4 v1 = *(const float4*)(src + 4);
        *(short8*)(Wbf + ((size_t)(m * 32 + kc) * 256 + d) * 8) = pack8(v0, v1);
    }
    if (t < H_) {
        float s = 0.f;
#pragma unroll
        for (int i = 0; i < 5; ++i) s += bias[i * H_ + t];
        bsum[t] = s;
    }
}

// R0-R7 diagnostic: flat ~2.5 TB/s effective BW across every structure =
// read-duty-cycle limit, not fabric. Each prior block alternated read-burst
// with read-silence (latency-chained K-loop W loads: VGPR_Count 44 -> no
// hoisting; ~2400 cyc of L2 chains per tile with zero HBM reads in flight).
//
// This version: 1 block/CU (512 thr, 8 waves as (rh,ds)); per (b,parity)
// M=255 GEMM in 4x64-row tiles.
//  - W HOISTED TO REGISTERS once per block (32 b128/lane = 128 VGPR): the
//    K-loop is pure LDS+MFMA (~1.5K cyc), no latency chains.
//  - x double-buffered in LDS (2x64 KB) via global_load_lds with the m173
//    pre-swizzled-source pattern; stage(t+1) is issued right after the
//    barrier and flies during ALL of compute t -> continuous HBM reads.
//  - Verified 2-phase template sync: raw s_barrier + vmcnt(0) at iter top
//    (stage(t+1) not yet issued -> only stage(t)+old stores drain).
// s in {0,1,2} handled by 6 edge blocks (bid 0-5, launched first) that read
// W0-2 from L2 in-loop.
template <int MODE>
__global__ __launch_bounds__(512, 2)
void sel_gemm_kernel(const float* __restrict__ x,
                     const void* __restrict__ Wp,
                     const void* __restrict__ bp,
                     float* __restrict__ out) {
    __shared__ float As[2][64 * 256];       // 128 KB double buffer

    const int bid  = blockIdx.x;
    const int t    = threadIdx.x;
    const int lane = t & 63;
    const int w8   = t >> 6;        // 0..7
    const int ds   = w8 & 3;        // d-slice: ds*64
    const int rh   = w8 >> 2;       // row half within 64-row tile
    const int lrow = lane & 15;
    const int quad = lane >> 4;

    const bool edge = (bid < 6);
    int m_idx, rstride, rmaxg;
    size_t xrow0;                   // float-row index (into x/out) of r=0
    if (edge) {
        const int s  = bid >> 1;    // 0..2
        const int bh = bid & 1;
        m_idx   = s;
        xrow0   = (size_t)(bh * 64) * S_ + s;   // row r -> b = bh*64+r
        rstride = S_;
        rmaxg   = 63;
    } else {
        const int mb = bid - 6;     // 0..255
        const int p  = mb & 1;
        m_idx   = p ? 3 : 4;
        xrow0   = (size_t)(mb >> 1) * S_ + (p ? 3 : 4);  // row r -> s=sb+2r
        rstride = 2;
        rmaxg   = 254;
    }

    // Stage 64 rows x 256 fp32 into As[buf]. One gload_lds = one full row
    // (wave-uniform LDS base + lane*16). Per-lane GLOBAL chunk = lane^(r&7)
    // so LDS chunk c holds global chunk c^(r&7) (read applies same XOR).
    auto stage = [&](int buf, int rbase) {
#pragma unroll
        for (int it = 0; it < 8; ++it) {
            const int row = w8 * 8 + it;        // local 0..63
            int rg = rbase + row;
            if (rg > rmaxg) rg = rmaxg;         // clamp data; slot stays row
            const float* src = x + (xrow0 + (size_t)rstride * rg) * H_
                                 + ((lane ^ (row & 7)) << 2);
            __builtin_amdgcn_global_load_lds(
                (const __attribute__((address_space(1))) unsigned int*)src,
                (__attribute__((address_space(3))) unsigned int*)&As[buf][row * 256],
                16, 0, 0);
        }
    };

    // ---- Bias along this wave's d-slice.
    f32x4 bj4[4];
    if (MODE == 0) {
        const float* bsum = (const float*)bp;
#pragma unroll
        for (int j = 0; j < 4; ++j)
            bj4[j] = *(const f32x4*)(bsum + ds * 64 + j * 16 + quad * 4);
    } else {
        const float* bias = (const float*)bp;
#pragma unroll
        for (int j = 0; j < 4; ++j) {
            const int d0 = ds * 64 + j * 16 + quad * 4;
#pragma unroll
            for (int r = 0; r < 4; ++r) {
                float sum = 0.f;
#pragma unroll
                for (int i = 0; i < 5; ++i) sum += bias[i * H_ + d0 + r];
                bj4[j][r] = sum;
            }
        }
    }

    if (!edge) {
        stage(0, 0);
        __builtin_amdgcn_sched_barrier(0);

        // ---- W-hoist: this wave's 64-d slice, all K=256 -> 32 short8.
        // Issued after stage(0): L2 latency hides under the HBM stage.
        short8 wfr[4][8];
        if (MODE == 0) {
            const unsigned short* Wb = (const unsigned short*)Wp;
#pragma unroll
            for (int kk = 0; kk < 8; ++kk) {
                const unsigned short* Wk =
                    Wb + ((size_t)(m_idx * 32 + kk * 4 + quad) * 256) * 8;
#pragma unroll
                for (int j = 0; j < 4; ++j)
                    wfr[j][kk] = *(const short8*)(Wk +
                                  (size_t)(ds * 64 + j * 16 + lrow) * 8);
            }
        } else {
            const float* Wb = (const float*)Wp + (size_t)m_idx * H_ * H_;
#pragma unroll
            for (int kk = 0; kk < 8; ++kk)
#pragma unroll
                for (int j = 0; j < 4; ++j) {
                    const float* wrow = Wb +
                        (size_t)(ds * 64 + j * 16 + lrow) * H_ + kk * 32 + quad * 8;
                    float4 v0 = *(const float4*)wrow;
                    float4 v1 = *(const float4*)(wrow + 4);
                    wfr[j][kk] = pack8(v0, v1);
                }
        }

#pragma unroll
        for (int tt = 0; tt < 4; ++tt) {
            // stage(tt) complete? (stage(tt+1) not yet issued -> vmcnt(0)
            // drains only stage(tt) + retired-anyway old stores)
            asm volatile("s_waitcnt vmcnt(0)" ::: "memory");
            __builtin_amdgcn_s_barrier();
            __builtin_amdgcn_sched_barrier(0);
            if (tt < 3) {
                stage((tt + 1) & 1, (tt + 1) * 64);   // flies during compute
                __builtin_amdgcn_sched_barrier(0);
            }

            const float* Ab = As[tt & 1];
            f32x4 acc[2][4];
#pragma unroll
            for (int i = 0; i < 2; ++i)
#pragma unroll
                for (int j = 0; j < 4; ++j) {
                    f32x4 z = {0.f, 0.f, 0.f, 0.f};
                    acc[i][j] = z;
                }

            // Pure LDS+register K-loop: 8 steps of 32.
#pragma unroll
            for (int kk = 0; kk < 8; ++kk) {
                short8 xfr[2];
                const int g0 = kk * 8 + quad * 2;   // global 16B-chunk idx
#pragma unroll
                for (int i = 0; i < 2; ++i) {
                    const int r = rh * 32 + i * 16 + lrow;
                    f32x4 f0 = *(const f32x4*)&Ab[r * 256 + (((g0    ) ^ (r & 7)) << 2)];
                    f32x4 f1 = *(const f32x4*)&Ab[r * 256 + (((g0 + 1) ^ (r & 7)) << 2)];
                    xfr[i] = pack8v(f0, f1);
                }
#pragma unroll
                for (int j = 0; j < 4; ++j)
#pragma unroll
                    for (int i = 0; i < 2; ++i)
                        acc[i][j] = __builtin_amdgcn_mfma_f32_16x16x32_bf16(
                            wfr[j][kk], xfr[i], acc[i][j], 0, 0, 0);
            }

            // Epilogue: col(lane&15)=tile row, row(quad*4+reg)=d.
#pragma unroll
            for (int j = 0; j < 4; ++j) {
                const int d0 = ds * 64 + j * 16 + quad * 4;
#pragma unroll
                for (int i = 0; i < 2; ++i) {
                    const int rg = tt * 64 + rh * 32 + i * 16 + lrow;
                    if (rg <= rmaxg) {
                        f32x4 v = acc[i][j] + bj4[j];
                        *(f32x4*)(out + (xrow0 + (size_t)rstride * rg) * H_ + d0) = v;
                    }
                }
            }
        }
    } else {
        // ---- Edge: single 64-row tile, W0-2 from L2 inside the K-loop.
        stage(0, 0);
        asm volatile("s_waitcnt vmcnt(0)" ::: "memory");
        __builtin_amdgcn_s_barrier();
        __builtin_amdgcn_sched_barrier(0);

        f32x4 acc[2][4];
#pragma unroll
        for (int i = 0; i < 2; ++i)
#pragma unroll
            for (int j = 0; j < 4; ++j) {
                f32x4 z = {0.f, 0.f, 0.f, 0.f};
                acc[i][j] = z;
            }

#pragma unroll
        for (int kk = 0; kk < 8; ++kk) {
            short8 wfr[4];
            if (MODE == 0) {
                const unsigned short* Wk =
                    (const unsigned short*)Wp +
                    ((size_t)(m_idx * 32 + kk * 4 + quad) * 256) * 8;
#pragma unroll
                for (int j = 0; j < 4; ++j)
                    wfr[j] = *(const short8*)(Wk +
                              (size_t)(ds * 64 + j * 16 + lrow) * 8);
            } else {
                const float* Wb = (const float*)Wp + (size_t)m_idx * H_ * H_;
#pragma unroll
                for (int j = 0; j < 4; ++j) {
                    const float* wrow = Wb +
                        (size_t)(ds * 64 + j * 16 + lrow) * H_ + kk * 32 + quad * 8;
                    float4 v0 = *(const float4*)wrow;
                    float4 v1 = *(const float4*)(wrow + 4);
                    wfr[j] = pack8(v0, v1);
                }
            }

            short8 xfr[2];
            const int g0 = kk * 8 + quad * 2;
#pragma unroll
            for (int i = 0; i < 2; ++i) {
                const int r = rh * 32 + i * 16 + lrow;
                f32x4 f0 = *(const f32x4*)&As[0][r * 256 + (((g0    ) ^ (r & 7)) << 2)];
                f32x4 f1 = *(const f32x4*)&As[0][r * 256 + (((g0 + 1) ^ (r & 7)) << 2)];
                xfr[i] = pack8v(f0, f1);
            }

#pragma unroll
            for (int j = 0; j < 4; ++j)
#pragma unroll
                for (int i = 0; i < 2; ++i)
                    acc[i][j] = __builtin_amdgcn_mfma_f32_16x16x32_bf16(
                        wfr[j], xfr[i], acc[i][j], 0, 0, 0);
        }

#pragma unroll
        for (int j = 0; j < 4; ++j) {
            const int d0 = ds * 64 + j * 16 + quad * 4;
#pragma unroll
            for (int i = 0; i < 2; ++i) {
                const int rg = rh * 32 + i * 16 + lrow;
                f32x4 v = acc[i][j] + bj4[j];
                *(f32x4*)(out + (xrow0 + (size_t)rstride * rg) * H_ + d0) = v;
            }
        }
    }
}

extern "C" void kernel_launch(void* const* d_in, const int* in_sizes, int n_in,
                              void* d_out, int out_size, void* d_ws, size_t ws_size,
                              hipStream_t stream) {
    const float* x    = (const float*)d_in[0];
    const float* W    = (const float*)d_in[1];
    const float* bias = (const float*)d_in[2];
    float* out = (float*)d_out;

    const size_t w_elems  = (size_t)5 * H_ * H_;
    const size_t ws_need  = w_elems * sizeof(unsigned short) + H_ * sizeof(float);

    const int grid = 6 + 256;
    if (ws_size >= ws_need) {
        unsigned short* Wbf = (unsigned short*)d_ws;
        float* bsum = (float*)((char*)d_ws + w_elems * sizeof(unsigned short));
        prep_kernel<<<dim3(160), dim3(256), 0, stream>>>(W, bias, Wbf, bsum);
        sel_gemm_kernel<0><<<dim3(grid), dim3(512), 0, stream>>>(
            x, (const void*)Wbf, (const void*)bsum, out);
    } else {
        sel_gemm_kernel<1><<<dim3(grid), dim3(512), 0, stream>>>(
            x, (const void*)W, (const void*)bias, out);
    }
}